// Round 10
// baseline (635.279 us; speedup 1.0000x reference)
//
#include <hip/hip_runtime.h>
#include <hip/hip_bf16.h>
#include <math.h>

typedef float f4 __attribute__((ext_vector_type(4)));
typedef float f32x4 __attribute__((ext_vector_type(4)));
typedef __bf16 bf16x8 __attribute__((ext_vector_type(8)));
typedef unsigned int uint32x4 __attribute__((ext_vector_type(4)));

#define NT 256

// ---------------------------------------------------------------------------
// Weight repack into MFMA B-fragment order (16x16x32 bf16).
// B-frag: lane l holds B[k = (l>>4)*8 + j][co = l&15], j = 0..7 (16B/lane).
// Element index: ((kstep * NTILES + n) * 64 + l) * 8 + j
//   pk2: kstep=tap*4+cs (36), NTILES=8  -> elems [0, 147456)
//   pk3: kstep=tap*4+cs (36), NTILES=4  -> elems [147456, 221184)
//   pk4: kstep=tap*2+half (18), NTILES=4 -> elems [221184, 258048)
//   pk1: kstep=0 (1, K=32 zero-padded), NTILES=8 -> elems [258048, 262144)
// ---------------------------------------------------------------------------
__global__ void repack_w(const float* __restrict__ w1, const float* __restrict__ w2,
                         const float* __restrict__ w3, const float* __restrict__ w4,
                         __hip_bfloat16* __restrict__ ws)
{
    int tid = blockIdx.x * 256 + threadIdx.x;
    const int T2 = 147456, T3 = 73728, T4 = 36864, T1 = 4096;
    if (tid < T2) {
        int j = tid & 7, l = (tid >> 3) & 63, rest = tid >> 9;
        int n = rest & 7, kidx = rest >> 3;      // tap*4+cs
        int cs = kidx & 3, tap = kidx >> 2;
        int ci = cs * 32 + ((l >> 4) << 3) + j;
        int co = (n << 4) + (l & 15);
        ws[tid] = __float2bfloat16(w2[(tap * 128 + ci) * 128 + co]);
    } else if (tid < T2 + T3) {
        int t3 = tid - T2;
        int j = t3 & 7, l = (t3 >> 3) & 63, rest = t3 >> 9;
        int n = rest & 3, kidx = rest >> 2;
        int cs = kidx & 3, tap = kidx >> 2;
        int ci = cs * 32 + ((l >> 4) << 3) + j;
        int co = (n << 4) + (l & 15);
        ws[tid] = __float2bfloat16(w3[(tap * 128 + ci) * 64 + co]);
    } else if (tid < T2 + T3 + T4) {
        int t4 = tid - T2 - T3;
        int j = t4 & 7, l = (t4 >> 3) & 63, rest = t4 >> 9;
        int n = rest & 3, ks = rest >> 2;        // tap*2+half
        int half = ks & 1, tap = ks >> 1;
        int ci = half * 32 + ((l >> 4) << 3) + j;
        int co = (n << 4) + (l & 15);
        ws[tid] = __float2bfloat16(w4[(tap * 64 + ci) * 64 + co]);
    } else if (tid < T2 + T3 + T4 + T1) {
        int t1 = tid - T2 - T3 - T4;
        int j = t1 & 7, l = (t1 >> 3) & 63, n = (t1 >> 9) & 7;
        int k = ((l >> 4) << 3) + j;             // tap index, 0..31
        int co = (n << 4) + (l & 15);
        float v = (k < 9) ? w1[k * 128 + co] : 0.f;
        ws[tid] = __float2bfloat16(v);
    }
}

// ---------------------------------------------------------------------------
// Fused network, one block per image. Activation layouts (k-major fragment):
//   addr = base + (ci>>3)*KBSTRIDE + row*16 + (ci&7)*2  (bf16)
//   act1T: base 0,     16 kb, stride 1616 (rows 0..99 + zero row 100)
//   xp:    f32 [50][132] x-pooled conv2 staging at [0, 26400)  (132 = +4 pad
//          -> store banks (4s+co)%32, exact 2-way = free; 128 was 4-way)
//   p2bT:  base 26400, 16 kb, stride 416 (rows 0..24 + zero row 25)
//   act3T: base 0,      8 kb, stride 416 (rows 0..24 + zero row 25)
// conv2: 7 M-tiles x 2 N-tiles per wave, NO B-prefetch; per-cs T19
// sched_group_barrier {2 VMEM_READ, 7x(1 DS_READ, 2 MFMA)} pins the
// interleave so the scheduler cannot hoist loads across cs-steps
// (that hoisting = ~60 live regs = the r4/r6 spill at the 4-wave bound).
// Target: 4 blocks/CU (bounds (256,4)), ~105 regs/wave, no scratch.
// ---------------------------------------------------------------------------
__global__ __launch_bounds__(NT, 4)
void img2svg_fused(const float* __restrict__ data,
                   const float* __restrict__ b1, const float* __restrict__ b2,
                   const float* __restrict__ b3, const float* __restrict__ b4,
                   const float* __restrict__ wd1, const float* __restrict__ bd1,
                   const float* __restrict__ wd2, const float* __restrict__ bd2,
                   const __hip_bfloat16* __restrict__ wsb,
                   float* __restrict__ out)
{
    __shared__ __align__(16) unsigned char s_u[33280];
    __shared__ float s_in[144];
    __shared__ float s_pool4[4 * 64];
    __shared__ float s_feat[64];
    __shared__ float s_h[32];

    const int t = threadIdx.x;
    const int img = blockIdx.x;
    const int w = t >> 6;
    const int lane = t & 63;
    const int kg = lane >> 4;
    const int l15 = lane & 15;
    const int kgbase1 = kg * 1616;
    const int kgbase2 = kg * 416;

    // ---------------- P0: stage input, zero act1T row 100 ----------------
    if (t < 144) {
        int r = t / 12, c = t % 12;
        float v = 0.f;
        if (r >= 1 && r <= 10 && c >= 1 && c <= 10)
            v = data[img * 100 + (r - 1) * 10 + (c - 1)];
        s_in[t] = v;
    }
    if (t < 128)
        *(__bf16*)(s_u + (t >> 3) * 1616 + 1600 + (t & 7) * 2) = (__bf16)0.f;
    s_pool4[t] = 0.f;
    __syncthreads();

    // ---------------- P1: conv1 (1->128) via MFMA, K=32 zero-padded ----------------
    {
        const uint32x4* pk1v = (const uint32x4*)((const __hip_bfloat16*)wsb + 258048);
        uint32x4 B0 = pk1v[((w * 2 + 0) << 6) + lane];
        uint32x4 B1 = pk1v[((w * 2 + 1) << 6) + lane];
        float bj0 = b1[(w * 2 + 0) * 16 + l15];
        float bj1 = b1[(w * 2 + 1) * 16 + l15];
        const int kb0 = (w * 2 + 0) * 2 + (l15 >> 3);
        const int kb1 = (w * 2 + 1) * 2 + (l15 >> 3);
        const int cb = (l15 & 7) * 2;

        for (int mi = 0; mi < 7; ++mi) {
            int p_raw = mi * 16 + l15;
            int p = p_raw < 100 ? p_raw : 99;
            int y = p / 10, x = p - 10 * (p / 10);
            bf16x8 A = __builtin_bit_cast(bf16x8, (uint32x4){0, 0, 0, 0});
            if (kg == 0) {
#pragma unroll
                for (int j = 0; j < 8; ++j)
                    A[j] = (__bf16)s_in[(y + j / 3) * 12 + x + j % 3];
            } else if (kg == 1) {
                A[0] = (__bf16)s_in[(y + 2) * 12 + x + 2];
            }
            f32x4 c0 = (f32x4){bj0, bj0, bj0, bj0};
            f32x4 c1 = (f32x4){bj1, bj1, bj1, bj1};
            c0 = __builtin_amdgcn_mfma_f32_16x16x32_bf16(
                A, __builtin_bit_cast(bf16x8, B0), c0, 0, 0, 0);
            c1 = __builtin_amdgcn_mfma_f32_16x16x32_bf16(
                A, __builtin_bit_cast(bf16x8, B1), c1, 0, 0, 0);
#pragma unroll
            for (int rr = 0; rr < 4; ++rr) {
                int p_out = mi * 16 + kg * 4 + rr;
                if (p_out < 100) {
                    *(__bf16*)(s_u + kb0 * 1616 + p_out * 16 + cb) =
                        (__bf16)fmaxf(c0[rr], 0.f);
                    *(__bf16*)(s_u + kb1 * 1616 + p_out * 16 + cb) =
                        (__bf16)fmaxf(c1[rr], 0.f);
                }
            }
        }
    }
    __syncthreads();

    // ---------------- P2: conv2 (128->128) MFMA, 7 M x 2 N per wave ----------------
    {
        const uint32x4* pk2v = (const uint32x4*)wsb;

        f32x4 acc[7][2];
#pragma unroll
        for (int j = 0; j < 2; ++j) {
            float bj = b2[(w * 2 + j) * 16 + l15];
#pragma unroll
            for (int mi = 0; mi < 7; ++mi) acc[mi][j] = (f32x4){bj, bj, bj, bj};
        }

        int pos[7];
#pragma unroll
        for (int mi = 0; mi < 7; ++mi) pos[mi] = mi * 16 + l15;

        for (int tap = 0; tap < 9; ++tap) {
            const int dy = tap / 3, dx = tap - 3 * (tap / 3);
            int ao[7];
#pragma unroll
            for (int mi = 0; mi < 7; ++mi) {
                int py = pos[mi] / 10;
                int px = pos[mi] - 10 * py;
                int ay = py + dy - 1, ax = px + dx - 1;
                int r = ((unsigned)ay < 10u && (unsigned)ax < 10u) ? ay * 10 + ax : 100;
                ao[mi] = (r << 4) + kgbase1;
            }
#pragma unroll
            for (int cs = 0; cs < 4; ++cs) {
                int ks = tap * 4 + cs;
                uint32x4 Bc0 = pk2v[(((ks << 3) + w * 2 + 0) << 6) + lane];
                uint32x4 Bc1 = pk2v[(((ks << 3) + w * 2 + 1) << 6) + lane];
#pragma unroll
                for (int mi = 0; mi < 7; ++mi) {
                    bf16x8 A = *(const bf16x8*)(const void*)(s_u + cs * 6464 + ao[mi]);
                    acc[mi][0] = __builtin_amdgcn_mfma_f32_16x16x32_bf16(
                        A, __builtin_bit_cast(bf16x8, Bc0), acc[mi][0], 0, 0, 0);
                    acc[mi][1] = __builtin_amdgcn_mfma_f32_16x16x32_bf16(
                        A, __builtin_bit_cast(bf16x8, Bc1), acc[mi][1], 0, 0, 0);
                }
                // T19 pin: 2 B-loads, then 1 A-read : 2 MFMA x7. Prevents the
                // scheduler from hoisting loads across cs (reg-pressure cap).
                __builtin_amdgcn_sched_group_barrier(0x020, 2, 0);   // VMEM_READ
#pragma unroll
                for (int g = 0; g < 7; ++g) {
                    __builtin_amdgcn_sched_group_barrier(0x100, 1, 0); // DS_READ
                    __builtin_amdgcn_sched_group_barrier(0x008, 2, 0); // MFMA
                }
            }
        }
        __syncthreads();   // all waves done reading act1T

        // relu + x-pool in-register -> xp[50][132] f32 (padded, conflict-free)
        float* xp = (float*)s_u;
#pragma unroll
        for (int mi = 0; mi < 7; ++mi) {
            int posb = mi * 16 + kg * 4;
            if (mi < 6 || kg == 0) {
                int s = posb >> 1;               // x-pooled slot
#pragma unroll
                for (int j = 0; j < 2; ++j) {
                    int co = (w * 2 + j) * 16 + l15;
                    float m01 = fmaxf(fmaxf(acc[mi][j][0], acc[mi][j][1]), 0.f);
                    float m23 = fmaxf(fmaxf(acc[mi][j][2], acc[mi][j][3]), 0.f);
                    xp[s * 132 + co] = m01;
                    xp[(s + 1) * 132 + co] = m23;
                }
            }
        }
    }
    __syncthreads();

    // ---------------- P2b: y-pool + cvt -> p2bT bf16 (k-major); zero row 25 ----------------
    {
        const float* xp = (const float*)s_u;
        for (int i = t; i < 3200; i += NT) {
            int r = i >> 7, c = i & 127;
            int y2 = r / 5, x2 = r - 5 * y2;
            int s = y2 * 10 + x2;
            float v = fmaxf(xp[s * 132 + c], xp[(s + 5) * 132 + c]);
            *(__bf16*)(s_u + 26400 + (c >> 3) * 416 + (r << 4) + (c & 7) * 2) = (__bf16)v;
        }
        if (t < 128)
            *(__bf16*)(s_u + 26400 + (t >> 3) * 416 + 400 + (t & 7) * 2) = (__bf16)0.f;
    }
    __syncthreads();

    // ---------------- P3: conv3 (128->64) MFMA, M=32, N=64, K=1152 ----------------
    {
        if (t < 64)   // zero act3T row 25 (xp is dead now; act3T base 0)
            *(__bf16*)(s_u + (t >> 3) * 416 + 400 + (t & 7) * 2) = (__bf16)0.f;

        const int mt = w & 1, ntp = w >> 1;
        const uint32x4* pk3v = (const uint32x4*)((const __hip_bfloat16*)wsb + 147456);

        f32x4 c3[2];
#pragma unroll
        for (int j = 0; j < 2; ++j) {
            float bj = b3[ntp * 32 + j * 16 + l15];
            c3[j] = (f32x4){bj, bj, bj, bj};
        }
        int pos = mt * 16 + l15;
        int p3y = pos / 5, p3x = pos - 5 * (pos / 5);

        uint32x4 Bc[2], Bn[2];
#pragma unroll
        for (int j = 0; j < 2; ++j) Bc[j] = pk3v[((ntp * 2 + j) << 6) + lane];

        for (int tap = 0; tap < 9; ++tap) {
            const int dy = tap / 3, dx = tap - 3 * (tap / 3);
            int ay = p3y + dy - 1, ax = p3x + dx - 1;
            int r = ((unsigned)ay < 5u && (unsigned)ax < 5u) ? ay * 5 + ax : 25;
            int ao = 26400 + (r << 4) + kgbase2;
#pragma unroll
            for (int cs = 0; cs < 4; ++cs) {
                int nk = tap * 4 + cs + 1;
                if (nk < 36) {
#pragma unroll
                    for (int j = 0; j < 2; ++j)
                        Bn[j] = pk3v[(((nk << 2) + ntp * 2 + j) << 6) + lane];
                }
                bf16x8 A = *(const bf16x8*)(const void*)(s_u + cs * 1664 + ao);
#pragma unroll
                for (int j = 0; j < 2; ++j)
                    c3[j] = __builtin_amdgcn_mfma_f32_16x16x32_bf16(
                        A, __builtin_bit_cast(bf16x8, Bc[j]), c3[j], 0, 0, 0);
#pragma unroll
                for (int j = 0; j < 2; ++j) Bc[j] = Bn[j];
            }
        }
        // epilogue: relu, store bf16 act3T (k-major, base 0)
#pragma unroll
        for (int j = 0; j < 2; ++j) {
            int co = ntp * 32 + j * 16 + l15;
            int kb = co >> 3, cb = (co & 7) * 2;
#pragma unroll
            for (int rr = 0; rr < 4; ++rr) {
                int p = mt * 16 + kg * 4 + rr;
                if (p < 25)
                    *(__bf16*)(s_u + kb * 416 + p * 16 + cb) =
                        (__bf16)fmaxf(c3[j][rr], 0.f);
            }
        }
    }
    __syncthreads();

    // ---------------- P4: conv4 (64->64) MFMA, M=16, N=64, K=576 + pool ----------------
    {
        const int nt = w;
        const uint32x4* pk4v = (const uint32x4*)((const __hip_bfloat16*)wsb + 221184);
        float bj = b4[nt * 16 + l15];
        f32x4 c4 = (f32x4){bj, bj, bj, bj};
        int py = l15 >> 2, px = l15 & 3;

        uint32x4 Bc = pk4v[(nt << 6) + lane], Bn;
        for (int ks = 0; ks < 18; ++ks) {
            if (ks < 17) Bn = pk4v[((((ks + 1) << 2) + nt) << 6) + lane];
            int half = ks & 1, tap = ks >> 1;
            int dy = tap / 3, dx = tap - 3 * (tap / 3);
            int ay = py + dy - 1, ax = px + dx - 1;
            int r = ((unsigned)ay < 5u && (unsigned)ax < 5u) ? ay * 5 + ax : 25;
            bf16x8 A = *(const bf16x8*)(const void*)(
                s_u + (half * 4 + kg) * 416 + (r << 4));
            c4 = __builtin_amdgcn_mfma_f32_16x16x32_bf16(
                A, __builtin_bit_cast(bf16x8, Bc), c4, 0, 0, 0);
            Bc = Bn;
        }
#pragma unroll
        for (int rr = 0; rr < 4; ++rr) {
            int p = kg * 4 + rr;
            int cell = ((p >> 2) >> 1) * 2 + ((p & 3) >> 1);
            float rv = fmaxf(c4[rr], 0.f);
            atomicMax((int*)&s_pool4[cell * 64 + nt * 16 + l15], __float_as_int(rv));
        }
    }
    __syncthreads();

    // ---------------- P5: mean + dense1 ----------------
    if (t < 64) {
        float f = 0.25f * (s_pool4[t] + s_pool4[64 + t] + s_pool4[128 + t] + s_pool4[192 + t]);
        s_feat[t] = f;
    }
    __syncthreads();
    if (t < 32) {
        float h = bd1[t];
        for (int i = 0; i < 64; ++i) h = fmaf(s_feat[i], wd1[i * 32 + t], h);
        s_h[t] = fmaxf(h, 0.f);
    }
    __syncthreads();

    // ---------------- P6: dense2 + sigmoid + bezier + round + sort + dedup ----------------
    if (t == 0) {
        float v[4];
#pragma unroll
        for (int o = 0; o < 4; ++o) {
            float vv = bd2[o];
            for (int i = 0; i < 32; ++i) vv = fmaf(s_h[i], wd2[i * 4 + o], vv);
            v[o] = 1.f / (1.f + expf(-vv));
        }
        float px[5], py[5], pp[5];
#pragma unroll
        for (int k = 0; k < 5; ++k) {
            float tk = 0.25f * (float)k;
            float gx = ((1.f - tk) * v[0] + tk * v[2]) * 10.f;
            float gy = ((1.f - tk) * v[1] + tk * v[3]) * 10.f;
            px[k] = rintf(gx);
            py[k] = rintf(gy);
            pp[k] = px[k] * 10.f + py[k];
        }
#pragma unroll
        for (int pass = 0; pass < 4; ++pass)
#pragma unroll
            for (int i = 0; i < 4 - pass; ++i) {
                bool sw = pp[i] > pp[i + 1];
                float a, b;
                a = pp[i]; b = pp[i + 1]; pp[i] = sw ? b : a; pp[i + 1] = sw ? a : b;
                a = px[i]; b = px[i + 1]; px[i] = sw ? b : a; px[i + 1] = sw ? a : b;
                a = py[i]; b = py[i + 1]; py[i] = sw ? b : a; py[i + 1] = sw ? a : b;
            }
        float* op = out + img * 10;
#pragma unroll
        for (int i = 0; i < 5; ++i) { op[2 * i] = -1.f; op[2 * i + 1] = -1.f; }
        int k2 = 0;
#pragma unroll
        for (int i = 0; i < 5; ++i) {
            bool keep;
            if (i == 0) keep = true;
            else keep = (fabsf(px[i] - px[i - 1]) + fabsf(py[i] - py[i - 1])) != 0.f;
            if (keep) {
                op[2 * k2] = px[i];
                op[2 * k2 + 1] = py[i];
                ++k2;
            }
        }
    }
}

extern "C" void kernel_launch(void* const* d_in, const int* in_sizes, int n_in,
                              void* d_out, int out_size, void* d_ws, size_t ws_size,
                              hipStream_t stream) {
    const float* data = (const float*)d_in[0];
    const float* w1  = (const float*)d_in[1];
    const float* b1  = (const float*)d_in[2];
    const float* w2  = (const float*)d_in[3];
    const float* b2  = (const float*)d_in[4];
    const float* w3  = (const float*)d_in[5];
    const float* b3  = (const float*)d_in[6];
    const float* w4  = (const float*)d_in[7];
    const float* b4  = (const float*)d_in[8];
    const float* wd1 = (const float*)d_in[9];
    const float* bd1 = (const float*)d_in[10];
    const float* wd2 = (const float*)d_in[11];
    const float* bd2 = (const float*)d_in[12];
    float* out = (float*)d_out;
    __hip_bfloat16* wsb = (__hip_bfloat16*)d_ws;

    repack_w<<<1024, 256, 0, stream>>>(w1, w2, w3, w4, wsb);

    int nimg = in_sizes[0] / 100;
    img2svg_fused<<<nimg, NT, 0, stream>>>(data, b1, b2, b3, b4,
                                           wd1, bd1, wd2, bd2, wsb, out);
}